// Round 4
// baseline (4117.342 us; speedup 1.0000x reference)
//
#include <hip/hip_runtime.h>
#include <hip/hip_bf16.h>
#include <math.h>

#define N_NODES 50000
#define N_EDGES 800000
#define N_GRAPHS 1024
#define HD 128
#define NLAYERS 5
#define EDGE_IN 41
#define NT 3
#define LN_EPS 1e-5f

typedef unsigned int uint;
typedef unsigned short ushort;
typedef __attribute__((ext_vector_type(8))) short short8;
typedef __attribute__((ext_vector_type(4))) float f32x4;

// fast silu: x * rcp(1+exp(-x)); v_rcp_f32 rel err ~1e-7 (vs 6.8e-4 threshold)
__device__ __forceinline__ float silu_f(float v) {
    return v * __builtin_amdgcn_rcpf(1.0f + __expf(-v));
}

// round-to-nearest-even f32 -> bf16 bits
__device__ __forceinline__ ushort f2bf(float f) {
    uint u = __float_as_uint(f);
    u = u + 0x7FFFu + ((u >> 16) & 1u);
    return (ushort)(u >> 16);
}

__device__ __forceinline__ short8 ld16(const ushort* p) {
    union { int4 i; short8 s; } u;
    u.i = *(const int4*)p;
    return u.s;
}

__device__ __forceinline__ f32x4 mfma16(short8 a, short8 b, f32x4 c) {
    return __builtin_amdgcn_mfma_f32_16x16x32_bf16(a, b, c, 0, 0, 0);
}

// wave-local LDS fence
__device__ __forceinline__ void wave_lds_fence() {
    __asm__ volatile("s_waitcnt lgkmcnt(0)" ::: "memory");
}

// async global->LDS, 16 B per lane; HW writes lane's data to ldsbase + lane*16
__device__ __forceinline__ void cp16(const ushort* g, ushort* l) {
    __builtin_amdgcn_global_load_lds(
        (const __attribute__((address_space(1))) unsigned int*)g,
        (__attribute__((address_space(3))) unsigned int*)l, 16, 0, 0);
}

// stage 4096 ushorts (8 KB): wave w covers [w*1024, +1024), lane-contig 16 B
__device__ __forceinline__ void stage4k(ushort* lds, const ushort* g, int w, int L) {
#pragma unroll
    for (int i = 0; i < 2; ++i) {
        int f = w * 1024 + i * 512;
        cp16(g + f + L * 8, lds + f);
    }
}

// ---------------- zero ----------------
__global__ void k_zero(float* __restrict__ p, int n) {
    int i = blockIdx.x * 256 + threadIdx.x;
    if (i < n) p[i] = 0.0f;
}

// ---------------- counting sort of edges by dst ----------------
__global__ void k_hist(const int* __restrict__ nbr_idx, int* __restrict__ cnt_i) {
    int i = blockIdx.x * 256 + threadIdx.x;
    if (i < N_EDGES) atomicAdd(&cnt_i[nbr_idx[2 * i + 1]], 1);
}

// single-block exclusive scan over cnt_i -> cur (start offsets); also cnt float for k_post
__global__ __launch_bounds__(256) void k_scan(
    const int* __restrict__ cnt_i, int* __restrict__ cur, float* __restrict__ cntf)
{
    __shared__ int warpsum[4];
    __shared__ int srun;
    int tid = threadIdx.x;
    int lane = tid & 63, wv = tid >> 6;
    if (tid == 0) srun = 0;
    __syncthreads();
    for (int base = 0; base < N_NODES; base += 256) {
        int i = base + tid;
        int c = (i < N_NODES) ? cnt_i[i] : 0;
        int s = c;
        for (int off = 1; off < 64; off <<= 1) {
            int t = __shfl_up(s, off);
            if (lane >= off) s += t;
        }
        if (lane == 63) warpsum[wv] = s;
        __syncthreads();
        int woff = 0;
        for (int k = 0; k < wv; ++k) woff += warpsum[k];
        int run = srun;
        if (i < N_NODES) {
            cur[i]  = run + woff + s - c;
            cntf[i] = (float)c;
        }
        __syncthreads();
        if (tid == 255) srun = run + woff + s;
    }
}

// scatter edges into dst-sorted order
__global__ void k_scatter(const int* __restrict__ nbr_idx, int* __restrict__ cur,
                          int* __restrict__ ssrc, int* __restrict__ sdst,
                          int* __restrict__ posof)
{
    int e = blockIdx.x * 256 + threadIdx.x;
    if (e < N_EDGES) {
        int s = nbr_idx[2 * e];
        int d = nbr_idx[2 * e + 1];
        int p = atomicAdd(&cur[d], 1);
        ssrc[p] = s;
        sdst[p] = d;
        posof[e] = p;
    }
}

// ---------------- weight swizzle: 16x16x32 B-fragment order ----------------
__global__ void k_swz_w1(const float* __restrict__ w1, ushort* __restrict__ w1s) {
    int i = blockIdx.x * 256 + threadIdx.x;            // 5 * 65536
    int l = i >> 16;
    int r = i & 65535;
    int j = r & 7, L = (r >> 3) & 63, s = (r >> 9) & 7, c = (r >> 12) & 15;
    int k = 32 * s + ((L >> 4) & 3) * 8 + j;
    int n = 16 * c + (L & 15);
    w1s[i] = f2bf(w1[(size_t)l * 65536 + k * 256 + n]);
}
__global__ void k_swz_w2(const float* __restrict__ w2, ushort* __restrict__ w2s) {
    int i = blockIdx.x * 256 + threadIdx.x;            // 5 * 32768
    int l = i >> 15;
    int r = i & 32767;
    int j = r & 7, L = (r >> 3) & 63, t = (r >> 9) & 7, s2 = (r >> 12) & 7;
    int k = 32 * s2 + ((L >> 4) & 3) * 8 + j;
    int n = 16 * t + (L & 15);
    w2s[i] = f2bf(w2[(size_t)l * 32768 + k * 128 + n]);
}

// ---------------- node embed: x = silu(LN(atom @ emb_w + emb_b)) ----------------
__global__ __launch_bounds__(128) void k_node_embed(
    const float* __restrict__ atom, const float* __restrict__ w,
    const float* __restrict__ b, const float* __restrict__ g,
    const float* __restrict__ bet, float* __restrict__ x, ushort* __restrict__ x_bf)
{
    int node = blockIdx.x;
    int h = threadIdx.x;
    float4 a = *(const float4*)(atom + (size_t)node * 4);
    float acc = b[h] + a.x * w[h] + a.y * w[HD + h] + a.z * w[2 * HD + h] + a.w * w[3 * HD + h];
    __shared__ float s1[2], s2[2];
    float sum = acc, sq = acc * acc;
    for (int off = 32; off > 0; off >>= 1) { sum += __shfl_down(sum, off); sq += __shfl_down(sq, off); }
    int wid = h >> 6, lane = h & 63;
    if (lane == 0) { s1[wid] = sum; s2[wid] = sq; }
    __syncthreads();
    float m = (s1[0] + s1[1]) * (1.0f / 128.0f);
    float v = (s2[0] + s2[1]) * (1.0f / 128.0f) - m * m;
    float y = (acc - m) * rsqrtf(v + LN_EPS) * g[h] + bet[h];
    y = silu_f(y);
    x[(size_t)node * HD + h] = y;
    x_bf[(size_t)node * HD + h] = f2bf(y);
}

// ---------------- edge embed -> bf16, written in dst-sorted position ----------------
#define ETILE 32
__global__ __launch_bounds__(128) void k_edge_embed(
    const float* __restrict__ fea, const float* __restrict__ w,
    const float* __restrict__ b, const int* __restrict__ posof,
    ushort* __restrict__ e_bf)
{
    __shared__ float sf[ETILE][EDGE_IN + 1];
    int e0 = blockIdx.x * ETILE;
    int tid = threadIdx.x;
    for (int i = tid; i < ETILE * EDGE_IN; i += 128) {
        int m = i / EDGE_IN, k = i % EDGE_IN;
        sf[m][k] = fea[(size_t)(e0 + m) * EDGE_IN + k];
    }
    __syncthreads();
    float bb = b[tid];
    float acc[ETILE];
#pragma unroll
    for (int m = 0; m < ETILE; m++) acc[m] = bb;
    for (int k = 0; k < EDGE_IN; k++) {
        float wk = w[k * HD + tid];
#pragma unroll
        for (int m = 0; m < ETILE; m++) acc[m] += sf[m][k] * wk;
    }
#pragma unroll
    for (int m = 0; m < ETILE; m++) {
        int p = posof[e0 + m];
        e_bf[(size_t)p * HD + tid] = f2bf(silu_f(acc[m]));
    }
}

// ---------------- graph counts ----------------
__global__ void k_gcount(const int* __restrict__ bm, float* __restrict__ gcnt) {
    int i = blockIdx.x * 256 + threadIdx.x;
    if (i < N_NODES) atomicAdd(&gcnt[bm[i]], 1.0f);
}

// ---------------- fused conv layer over dst-sorted edges ----------------
// MFMA pipeline: M=32 edges/wave, B-frags shared by 2 M-tiles, W1 double-
// buffered via global_load_lds. W2 SINGLE-buffered: chunk q staged at even
// pass 2q (prologue stages chunk 0), read only at odd pass 2q+1 -- the write
// lands under the barrier's vmcnt drain; the previous read of the buffer
// completed before the pass-2q barrier. LDS 43.5->35.3 KB => 4 blocks/CU.
// Epilogue: segmented reduction over dst-sorted edges (stride-18 sRed: both
// write (72B, bank+8/quad) and read (144B, bank+16/quad) are 2-way = free).
#define M1CP 40
#define RSTR 18
__global__ __launch_bounds__(256, 4) void k_conv_mfma(
    const ushort* __restrict__ x_bf, const ushort* __restrict__ e_bf,
    const int* __restrict__ ssrc, const int* __restrict__ sdst,
    const ushort* __restrict__ w1s, const float* __restrict__ cb1,
    const ushort* __restrict__ w2s, const float* __restrict__ cb2,
    float* __restrict__ aggr)
{
    __shared__ __align__(16) ushort sW1[2][4096];
    __shared__ __align__(16) ushort sW2[4096];
    __shared__ __align__(16) ushort sM1[4][32 * M1CP];
    __shared__ int sDst[128];

    int tid = threadIdx.x;
    int w = tid >> 6;
    int L = tid & 63;
    int m = L & 15;          // row/col-in-tile selector
    int quad = L >> 4;       // 0..3
    int eb = blockIdx.x * 128;
    int ew = eb + w * 32;    // wave's 32 edges

    if (tid < 128) sDst[tid] = sdst[eb + tid];

    // A-fragments loaded once: tile t edges ew + t*16 + m
    short8 af[2][8];
#pragma unroll
    for (int t = 0; t < 2; ++t) {
        int src = ssrc[ew + t * 16 + m];
        const ushort* xr = x_bf + (size_t)src * HD + quad * 8;
        const ushort* er = e_bf + (size_t)(ew + t * 16 + m) * HD + quad * 8;
#pragma unroll
        for (int s = 0; s < 4; ++s) af[t][s] = ld16(xr + 32 * s);
#pragma unroll
        for (int s = 0; s < 4; ++s) af[t][4 + s] = ld16(er + 32 * s);
    }

    f32x4 acc2[2][8];
#pragma unroll
    for (int t = 0; t < 2; ++t)
#pragma unroll
        for (int tt = 0; tt < 8; ++tt)
#pragma unroll
            for (int r = 0; r < 4; ++r) acc2[t][tt][r] = 0.0f;

    ushort* sm = sM1[w];

    // prologue: stage pass-0 W1 chunk and s2=0 W2 chunk
    stage4k(sW1[0], w1s, w, L);
    stage4k(sW2, w2s, w, L);

    for (int p = 0; p < 16; ++p) {
        __syncthreads();   // drains vmcnt -> current buffers ready
        // prefetch (overlaps compute below)
        if (p < 15) stage4k(sW1[(p + 1) & 1], w1s + (p + 1) * 4096, w, L);
        if (!(p & 1) && p >= 2)                       // stage W2 chunk p/2 (1..7)
            stage4k(sW2, w2s + (p >> 1) * 4096, w, L);

        // ---- GEMM1: cols [p*16, +16), both M-tiles share each B-frag ----
        f32x4 p0, p1;
#pragma unroll
        for (int r = 0; r < 4; ++r) { p0[r] = 0.0f; p1[r] = 0.0f; }
        const ushort* wb = sW1[p & 1] + L * 8;
#pragma unroll
        for (int s = 0; s < 8; ++s) {
            short8 wv = ld16(wb + s * 512);
            p0 = mfma16(af[0][s], wv, p0);
            p1 = mfma16(af[1][s], wv, p1);
        }

        // ---- bias + silu -> bf16 half-chunk (col = (p&1)*16 + m) ----
        float bv = cb1[p * 16 + m];
        int hb = (p & 1) * 16;
#pragma unroll
        for (int r = 0; r < 4; ++r) {
            sm[(quad * 4 + r) * M1CP + hb + m]        = f2bf(silu_f(p0[r] + bv));
            sm[(16 + quad * 4 + r) * M1CP + hb + m]   = f2bf(silu_f(p1[r] + bv));
        }

        // ---- odd pass: GEMM2 k-step s2 = p>>1 over the 32-col chunk ----
        if (p & 1) {
            wave_lds_fence();   // m1 writes (this+prev pass) complete
            short8 a20 = ld16(sm + m * M1CP + quad * 8);
            short8 a21 = ld16(sm + (16 + m) * M1CP + quad * 8);
            const ushort* w2p = sW2 + L * 8;
#pragma unroll
            for (int tt = 0; tt < 8; ++tt) {
                short8 bf = ld16(w2p + tt * 512);
                acc2[0][tt] = mfma16(a20, bf, acc2[0][tt]);
                acc2[1][tt] = mfma16(a21, bf, acc2[1][tt]);
            }
            wave_lds_fence();   // WAR: chunk halves reused next pass-pair
        }
    }

    // ---- epilogue: segmented reduce over sorted dsts, atomics at run ends ----
    float* sRed = (float*)sW1;          // 16 KB >= 128*RSTR*4 B, dead after last pass
    int tcol = tid & 15;                // 0..15
    int row0 = (tid >> 4) * 8;          // chunk of 8 rows
#pragma unroll
    for (int tt = 0; tt < 8; ++tt) {
        __syncthreads();                // prior reads of sRed/sW1 done
        float bv = cb2[tt * 16 + m];
#pragma unroll
        for (int t = 0; t < 2; ++t)
#pragma unroll
            for (int r = 0; r < 4; ++r)
                sRed[(w * 32 + t * 16 + quad * 4 + r) * RSTR + m] =
                    silu_f(acc2[t][tt][r] + bv);
        __syncthreads();
        // 256 threads: 16 cols x 16 chunks of 8 rows; segmented scan per chunk
        float s = sRed[row0 * RSTR + tcol];
        int cd = sDst[row0];
        for (int i = 1; i < 8; ++i) {
            int rr = row0 + i;
            int d2 = sDst[rr];
            float v = sRed[rr * RSTR + tcol];
            if (d2 == cd) {
                s += v;
            } else {
                atomicAdd(aggr + (size_t)cd * HD + tt * 16 + tcol, s);
                cd = d2;
                s = v;
            }
        }
        atomicAdd(aggr + (size_t)cd * HD + tt * 16 + tcol, s);
    }
}

// ---------------- post: x = LN(x + aggr/cnt); emit bf16; re-zero aggr ----------------
__global__ __launch_bounds__(128) void k_post(
    float* __restrict__ aggr, const float* __restrict__ cnt,
    const float* __restrict__ g, const float* __restrict__ bet,
    float* __restrict__ x, ushort* __restrict__ x_bf)
{
    int node = blockIdx.x;
    int h = threadIdx.x;
    float inv = __builtin_amdgcn_rcpf(fmaxf(cnt[node], 1.0f));
    float av = aggr[(size_t)node * HD + h];
    aggr[(size_t)node * HD + h] = 0.0f;          // ready for next layer's atomics
    float acc = x[(size_t)node * HD + h] + av * inv;
    __shared__ float s1[2], s2[2];
    float sum = acc, sq = acc * acc;
    for (int off = 32; off > 0; off >>= 1) { sum += __shfl_down(sum, off); sq += __shfl_down(sq, off); }
    int wid = h >> 6, lane = h & 63;
    if (lane == 0) { s1[wid] = sum; s2[wid] = sq; }
    __syncthreads();
    float m = (s1[0] + s1[1]) * (1.0f / 128.0f);
    float v = (s2[0] + s2[1]) * (1.0f / 128.0f) - m * m;
    float y = (acc - m) * rsqrtf(v + LN_EPS) * g[h] + bet[h];
    x[(size_t)node * HD + h] = y;
    x_bf[(size_t)node * HD + h] = f2bf(y);
}

// ---------------- graph pooling ----------------
__global__ __launch_bounds__(128) void k_gaggr(
    const float* __restrict__ x, const int* __restrict__ bm,
    float* __restrict__ crystal)
{
    int node = blockIdx.x;
    int h = threadIdx.x;
    atomicAdd(&crystal[(size_t)bm[node] * HD + h], x[(size_t)node * HD + h]);
}

// ---------------- readout MLP ----------------
__global__ __launch_bounds__(128) void k_readout(
    const float* __restrict__ crystal, const float* __restrict__ gcnt,
    const float* __restrict__ w1, const float* __restrict__ b1,
    const float* __restrict__ w2, const float* __restrict__ b2,
    const float* __restrict__ w3, const float* __restrict__ b3,
    float* __restrict__ out)
{
    int gph = blockIdx.x;
    int t = threadIdx.x;
    __shared__ float sc[HD], sh1[HD], sh2[64];
    float inv = __builtin_amdgcn_rcpf(fmaxf(gcnt[gph], 1.0f));
    sc[t] = crystal[(size_t)gph * HD + t] * inv;
    __syncthreads();
    float acc = b1[t];
    for (int k = 0; k < HD; k++) acc += sc[k] * w1[k * HD + t];
    sh1[t] = silu_f(acc);
    __syncthreads();
    if (t < 64) {
        float a2 = b2[t];
        for (int k = 0; k < HD; k++) a2 += sh1[k] * w2[k * 64 + t];
        sh2[t] = silu_f(a2);
    }
    __syncthreads();
    if (t < NT) {
        float a3 = b3[t];
        for (int k = 0; k < 64; k++) a3 += sh2[k] * w3[k * NT + t];
        out[(size_t)gph * NT + t] = a3;
    }
}

extern "C" void kernel_launch(void* const* d_in, const int* in_sizes, int n_in,
                              void* d_out, int out_size, void* d_ws, size_t ws_size,
                              hipStream_t stream)
{
    const float* atom_fea = (const float*)d_in[0];
    const float* nbr_fea  = (const float*)d_in[1];
    const int*   nbr_idx  = (const int*)d_in[2];
    const int*   bm       = (const int*)d_in[3];
    const float* emb_w    = (const float*)d_in[4];
    const float* emb_b    = (const float*)d_in[5];
    const float* emb_ln_g = (const float*)d_in[6];
    const float* emb_ln_b = (const float*)d_in[7];
    const float* edge_w   = (const float*)d_in[8];
    const float* edge_b   = (const float*)d_in[9];
    const float* conv_w1  = (const float*)d_in[10];
    const float* conv_b1  = (const float*)d_in[11];
    const float* conv_w2  = (const float*)d_in[12];
    const float* conv_b2  = (const float*)d_in[13];
    const float* ln_g     = (const float*)d_in[14];
    const float* ln_b     = (const float*)d_in[15];
    const float* out_w1   = (const float*)d_in[16];
    const float* out_b1   = (const float*)d_in[17];
    const float* out_w2   = (const float*)d_in[18];
    const float* out_b2   = (const float*)d_in[19];
    const float* out_w3   = (const float*)d_in[20];
    const float* out_b3   = (const float*)d_in[21];
    float* out = (float*)d_out;

    // ---- workspace layout (256B-aligned regions) ----
    char* base = (char*)d_ws;
    size_t off = 0;
    auto alloc = [&](size_t bytes) -> char* {
        char* p = base + off;
        off = (off + bytes + 255) & ~(size_t)255;
        return p;
    };
    float*  xbuf    = (float*) alloc((size_t)N_NODES * HD * 4);
    float*  aggr    = (float*) alloc((size_t)N_NODES * HD * 4);
    float*  cnt     = (float*) alloc((size_t)N_NODES * 4);
    float*  crystal = (float*) alloc((size_t)N_GRAPHS * HD * 4);
    float*  gcnt    = (float*) alloc((size_t)N_GRAPHS * 4);
    ushort* x_bf    = (ushort*)alloc((size_t)N_NODES * HD * 2);
    ushort* e_bf    = (ushort*)alloc((size_t)N_EDGES * HD * 2);
    ushort* w1s     = (ushort*)alloc((size_t)NLAYERS * 65536 * 2);
    ushort* w2s     = (ushort*)alloc((size_t)NLAYERS * 32768 * 2);
    int*    cnt_i   = (int*)   alloc((size_t)N_NODES * 4);
    int*    cur     = (int*)   alloc((size_t)N_NODES * 4);
    int*    ssrc    = (int*)   alloc((size_t)N_EDGES * 4);
    int*    sdst    = (int*)   alloc((size_t)N_EDGES * 4);
    int*    posof   = (int*)   alloc((size_t)N_EDGES * 4);

    // weights -> swizzled bf16
    k_swz_w1<<<(NLAYERS * 65536) / 256, 256, 0, stream>>>(conv_w1, w1s);
    k_swz_w2<<<(NLAYERS * 32768) / 256, 256, 0, stream>>>(conv_w2, w2s);

    // zero aggr (layer 0 only; k_post re-zeroes for later layers)
    k_zero<<<(N_NODES * HD) / 256, 256, 0, stream>>>(aggr, N_NODES * HD);
    // zero cnt + crystal + gcnt (contiguous region) and cnt_i
    int zn = N_NODES + N_GRAPHS * HD + N_GRAPHS + 128;
    k_zero<<<(zn + 255) / 256, 256, 0, stream>>>(cnt, zn);
    k_zero<<<(N_NODES + 255) / 256, 256, 0, stream>>>((float*)cnt_i, N_NODES);

    // counting sort of edges by dst
    k_hist<<<N_EDGES / 256, 256, 0, stream>>>(nbr_idx, cnt_i);
    k_scan<<<1, 256, 0, stream>>>(cnt_i, cur, cnt);
    k_scatter<<<N_EDGES / 256, 256, 0, stream>>>(nbr_idx, cur, ssrc, sdst, posof);

    k_node_embed<<<N_NODES, 128, 0, stream>>>(atom_fea, emb_w, emb_b, emb_ln_g, emb_ln_b, xbuf, x_bf);
    k_edge_embed<<<N_EDGES / ETILE, 128, 0, stream>>>(nbr_fea, edge_w, edge_b, posof, e_bf);
    k_gcount<<<(N_NODES + 255) / 256, 256, 0, stream>>>(bm, gcnt);

    for (int l = 0; l < NLAYERS; ++l) {
        k_conv_mfma<<<N_EDGES / 128, 256, 0, stream>>>(
            x_bf, e_bf, ssrc, sdst,
            w1s + (size_t)l * 65536, conv_b1 + (size_t)l * 256,
            w2s + (size_t)l * 32768, conv_b2 + (size_t)l * 128,
            aggr);
        k_post<<<N_NODES, 128, 0, stream>>>(aggr, cnt, ln_g + (size_t)l * HD, ln_b + (size_t)l * HD, xbuf, x_bf);
    }

    k_gaggr<<<N_NODES, 128, 0, stream>>>(xbuf, bm, crystal);
    k_readout<<<N_GRAPHS, 128, 0, stream>>>(crystal, gcnt, out_w1, out_b1, out_w2, out_b2, out_w3, out_b3, out);
}

// Round 5
// 2358.717 us; speedup vs baseline: 1.7456x; 1.7456x over previous
//
#include <hip/hip_runtime.h>
#include <hip/hip_bf16.h>
#include <math.h>

#define N_NODES 50000
#define N_EDGES 800000
#define N_GRAPHS 1024
#define HD 128
#define NLAYERS 5
#define EDGE_IN 41
#define NT 3
#define LN_EPS 1e-5f

typedef unsigned int uint;
typedef unsigned short ushort;
typedef __attribute__((ext_vector_type(8))) short short8;
typedef __attribute__((ext_vector_type(4))) float f32x4;

// fast silu: x * rcp(1+exp(-x)); v_rcp_f32 rel err ~1e-7 (vs 6.8e-4 threshold)
__device__ __forceinline__ float silu_f(float v) {
    return v * __builtin_amdgcn_rcpf(1.0f + __expf(-v));
}

// round-to-nearest-even f32 -> bf16 bits
__device__ __forceinline__ ushort f2bf(float f) {
    uint u = __float_as_uint(f);
    u = u + 0x7FFFu + ((u >> 16) & 1u);
    return (ushort)(u >> 16);
}

__device__ __forceinline__ short8 ld16(const ushort* p) {
    union { int4 i; short8 s; } u;
    u.i = *(const int4*)p;
    return u.s;
}

__device__ __forceinline__ f32x4 mfma16(short8 a, short8 b, f32x4 c) {
    return __builtin_amdgcn_mfma_f32_16x16x32_bf16(a, b, c, 0, 0, 0);
}

// wave-local LDS fence
__device__ __forceinline__ void wave_lds_fence() {
    __asm__ volatile("s_waitcnt lgkmcnt(0)" ::: "memory");
}

// async global->LDS, 16 B per lane; HW writes lane's data to ldsbase + lane*16
__device__ __forceinline__ void cp16(const ushort* g, ushort* l) {
    __builtin_amdgcn_global_load_lds(
        (const __attribute__((address_space(1))) unsigned int*)g,
        (__attribute__((address_space(3))) unsigned int*)l, 16, 0, 0);
}

// stage 4096 ushorts (8 KB): wave w covers [w*1024, +1024), lane-contig 16 B
__device__ __forceinline__ void stage4k(ushort* lds, const ushort* g, int w, int L) {
#pragma unroll
    for (int i = 0; i < 2; ++i) {
        int f = w * 1024 + i * 512;
        cp16(g + f + L * 8, lds + f);
    }
}

// ---------------- zero ----------------
__global__ void k_zero(float* __restrict__ p, int n) {
    int i = blockIdx.x * 256 + threadIdx.x;
    if (i < n) p[i] = 0.0f;
}

// ---------------- counting sort of edges by dst ----------------
__global__ void k_hist(const int* __restrict__ nbr_idx, int* __restrict__ cnt_i) {
    int i = blockIdx.x * 256 + threadIdx.x;
    if (i < N_EDGES) atomicAdd(&cnt_i[nbr_idx[2 * i + 1]], 1);
}

// single-block exclusive scan over cnt_i -> cur (start offsets); also cnt float for k_post
__global__ __launch_bounds__(256) void k_scan(
    const int* __restrict__ cnt_i, int* __restrict__ cur, float* __restrict__ cntf)
{
    __shared__ int warpsum[4];
    __shared__ int srun;
    int tid = threadIdx.x;
    int lane = tid & 63, wv = tid >> 6;
    if (tid == 0) srun = 0;
    __syncthreads();
    for (int base = 0; base < N_NODES; base += 256) {
        int i = base + tid;
        int c = (i < N_NODES) ? cnt_i[i] : 0;
        int s = c;
        for (int off = 1; off < 64; off <<= 1) {
            int t = __shfl_up(s, off);
            if (lane >= off) s += t;
        }
        if (lane == 63) warpsum[wv] = s;
        __syncthreads();
        int woff = 0;
        for (int k = 0; k < wv; ++k) woff += warpsum[k];
        int run = srun;
        if (i < N_NODES) {
            cur[i]  = run + woff + s - c;
            cntf[i] = (float)c;
        }
        __syncthreads();
        if (tid == 255) srun = run + woff + s;
    }
}

// scatter edges into dst-sorted order
__global__ void k_scatter(const int* __restrict__ nbr_idx, int* __restrict__ cur,
                          int* __restrict__ ssrc, int* __restrict__ sdst,
                          int* __restrict__ posof)
{
    int e = blockIdx.x * 256 + threadIdx.x;
    if (e < N_EDGES) {
        int s = nbr_idx[2 * e];
        int d = nbr_idx[2 * e + 1];
        int p = atomicAdd(&cur[d], 1);
        ssrc[p] = s;
        sdst[p] = d;
        posof[e] = p;
    }
}

// ---------------- weight swizzle: 16x16x32 B-fragment order ----------------
__global__ void k_swz_w1(const float* __restrict__ w1, ushort* __restrict__ w1s) {
    int i = blockIdx.x * 256 + threadIdx.x;            // 5 * 65536
    int l = i >> 16;
    int r = i & 65535;
    int j = r & 7, L = (r >> 3) & 63, s = (r >> 9) & 7, c = (r >> 12) & 15;
    int k = 32 * s + ((L >> 4) & 3) * 8 + j;
    int n = 16 * c + (L & 15);
    w1s[i] = f2bf(w1[(size_t)l * 65536 + k * 256 + n]);
}
__global__ void k_swz_w2(const float* __restrict__ w2, ushort* __restrict__ w2s) {
    int i = blockIdx.x * 256 + threadIdx.x;            // 5 * 32768
    int l = i >> 15;
    int r = i & 32767;
    int j = r & 7, L = (r >> 3) & 63, t = (r >> 9) & 7, s2 = (r >> 12) & 7;
    int k = 32 * s2 + ((L >> 4) & 3) * 8 + j;
    int n = 16 * t + (L & 15);
    w2s[i] = f2bf(w2[(size_t)l * 32768 + k * 128 + n]);
}

// ---------------- node embed: x = silu(LN(atom @ emb_w + emb_b)) ----------------
__global__ __launch_bounds__(128) void k_node_embed(
    const float* __restrict__ atom, const float* __restrict__ w,
    const float* __restrict__ b, const float* __restrict__ g,
    const float* __restrict__ bet, float* __restrict__ x, ushort* __restrict__ x_bf)
{
    int node = blockIdx.x;
    int h = threadIdx.x;
    float4 a = *(const float4*)(atom + (size_t)node * 4);
    float acc = b[h] + a.x * w[h] + a.y * w[HD + h] + a.z * w[2 * HD + h] + a.w * w[3 * HD + h];
    __shared__ float s1[2], s2[2];
    float sum = acc, sq = acc * acc;
    for (int off = 32; off > 0; off >>= 1) { sum += __shfl_down(sum, off); sq += __shfl_down(sq, off); }
    int wid = h >> 6, lane = h & 63;
    if (lane == 0) { s1[wid] = sum; s2[wid] = sq; }
    __syncthreads();
    float m = (s1[0] + s1[1]) * (1.0f / 128.0f);
    float v = (s2[0] + s2[1]) * (1.0f / 128.0f) - m * m;
    float y = (acc - m) * rsqrtf(v + LN_EPS) * g[h] + bet[h];
    y = silu_f(y);
    x[(size_t)node * HD + h] = y;
    x_bf[(size_t)node * HD + h] = f2bf(y);
}

// ---------------- edge embed -> bf16, written in dst-sorted position ----------------
#define ETILE 32
__global__ __launch_bounds__(128) void k_edge_embed(
    const float* __restrict__ fea, const float* __restrict__ w,
    const float* __restrict__ b, const int* __restrict__ posof,
    ushort* __restrict__ e_bf)
{
    __shared__ float sf[ETILE][EDGE_IN + 1];
    int e0 = blockIdx.x * ETILE;
    int tid = threadIdx.x;
    for (int i = tid; i < ETILE * EDGE_IN; i += 128) {
        int m = i / EDGE_IN, k = i % EDGE_IN;
        sf[m][k] = fea[(size_t)(e0 + m) * EDGE_IN + k];
    }
    __syncthreads();
    float bb = b[tid];
    float acc[ETILE];
#pragma unroll
    for (int m = 0; m < ETILE; m++) acc[m] = bb;
    for (int k = 0; k < EDGE_IN; k++) {
        float wk = w[k * HD + tid];
#pragma unroll
        for (int m = 0; m < ETILE; m++) acc[m] += sf[m][k] * wk;
    }
#pragma unroll
    for (int m = 0; m < ETILE; m++) {
        int p = posof[e0 + m];
        e_bf[(size_t)p * HD + tid] = f2bf(silu_f(acc[m]));
    }
}

// ---------------- graph counts ----------------
__global__ void k_gcount(const int* __restrict__ bm, float* __restrict__ gcnt) {
    int i = blockIdx.x * 256 + threadIdx.x;
    if (i < N_NODES) atomicAdd(&gcnt[bm[i]], 1.0f);
}

// ---------------- fused conv layer over dst-sorted edges ----------------
// R5: counted-vmcnt pipeline (T3/T4). W1 triple-buffered, W2 double-buffered,
// prefetch distance = 2 passes (~2x HBM latency). Per-pass sync is
// s_waitcnt vmcnt(4) + s_barrier (NOT __syncthreads' vmcnt(0) drain):
// the 4 newest outstanding loads are pass-(p-1)'s issues, so waiting to <=4
// retires everything issued at <=p-2, i.e. W1(p) and the W2 chunk needed.
// Tail passes 14/15 drain fully. sched_barrier(0) pins ds_reads after the
// barrier (cross-wave LDS visibility needs OTHER waves' vmcnt retire).
// Epilogue: segmented reduction over dst-sorted edges (stride-18 sRed).
#define M1CP 40
#define RSTR 18
__global__ __launch_bounds__(256, 3) void k_conv_mfma(
    const ushort* __restrict__ x_bf, const ushort* __restrict__ e_bf,
    const int* __restrict__ ssrc, const int* __restrict__ sdst,
    const ushort* __restrict__ w1s, const float* __restrict__ cb1,
    const ushort* __restrict__ w2s, const float* __restrict__ cb2,
    float* __restrict__ aggr)
{
    __shared__ __align__(16) ushort sW1[3][4096];
    __shared__ __align__(16) ushort sW2[2][4096];
    __shared__ __align__(16) ushort sM1[4][32 * M1CP];
    __shared__ int sDst[128];

    int tid = threadIdx.x;
    int w = tid >> 6;
    int L = tid & 63;
    int m = L & 15;          // row/col-in-tile selector
    int quad = L >> 4;       // 0..3
    int eb = blockIdx.x * 128;
    int ew = eb + w * 32;    // wave's 32 edges

    if (tid < 128) sDst[tid] = sdst[eb + tid];

    // A-fragments loaded once: tile t edges ew + t*16 + m
    short8 af[2][8];
#pragma unroll
    for (int t = 0; t < 2; ++t) {
        int src = ssrc[ew + t * 16 + m];
        const ushort* xr = x_bf + (size_t)src * HD + quad * 8;
        const ushort* er = e_bf + (size_t)(ew + t * 16 + m) * HD + quad * 8;
#pragma unroll
        for (int s = 0; s < 4; ++s) af[t][s] = ld16(xr + 32 * s);
#pragma unroll
        for (int s = 0; s < 4; ++s) af[t][4 + s] = ld16(er + 32 * s);
    }

    f32x4 acc2[2][8];
#pragma unroll
    for (int t = 0; t < 2; ++t)
#pragma unroll
        for (int tt = 0; tt < 8; ++tt)
#pragma unroll
            for (int r = 0; r < 4; ++r) acc2[t][tt][r] = 0.0f;

    ushort* sm = sM1[w];

    // prologue: W1 chunks 0,1 and W2 chunk 0 (issue order matters for vmcnt)
    stage4k(sW1[0], w1s, w, L);
    stage4k(sW1[1], w1s + 4096, w, L);
    stage4k(sW2[0], w2s, w, L);

    int rb = 0;  // read buffer = p % 3
    for (int p = 0; p < 16; ++p) {
        // counted wait: retires all loads issued at passes <= p-2
        if (p < 14) {
            __asm__ volatile("s_waitcnt vmcnt(4)" ::: "memory");
        } else {
            __asm__ volatile("s_waitcnt vmcnt(0)" ::: "memory");
        }
        __builtin_amdgcn_s_barrier();
        __builtin_amdgcn_sched_barrier(0);

        // distance-2 prefetch (stays in flight across the next barrier)
        int sb = rb + 2; if (sb >= 3) sb -= 3;          // (p+2) % 3
        if (p + 2 < 16) stage4k(sW1[sb], w1s + (p + 2) * 4096, w, L);
        if (!(p & 1) && (p >> 1) + 1 < 8)
            stage4k(sW2[((p >> 1) + 1) & 1], w2s + ((p >> 1) + 1) * 4096, w, L);

        // ---- GEMM1: cols [p*16, +16), both M-tiles share each B-frag ----
        f32x4 p0, p1;
#pragma unroll
        for (int r = 0; r < 4; ++r) { p0[r] = 0.0f; p1[r] = 0.0f; }
        const ushort* wb = sW1[rb] + L * 8;
#pragma unroll
        for (int s = 0; s < 8; ++s) {
            short8 wv = ld16(wb + s * 512);
            p0 = mfma16(af[0][s], wv, p0);
            p1 = mfma16(af[1][s], wv, p1);
        }

        // ---- bias + silu -> bf16 half-chunk (col = (p&1)*16 + m) ----
        float bv = cb1[p * 16 + m];
        int hb = (p & 1) * 16;
#pragma unroll
        for (int r = 0; r < 4; ++r) {
            sm[(quad * 4 + r) * M1CP + hb + m]        = f2bf(silu_f(p0[r] + bv));
            sm[(16 + quad * 4 + r) * M1CP + hb + m]   = f2bf(silu_f(p1[r] + bv));
        }

        // ---- odd pass: GEMM2 k-step s2 = p>>1 over the 32-col chunk ----
        if (p & 1) {
            wave_lds_fence();   // m1 writes (this+prev pass) complete
            short8 a20 = ld16(sm + m * M1CP + quad * 8);
            short8 a21 = ld16(sm + (16 + m) * M1CP + quad * 8);
            const ushort* w2p = sW2[(p >> 1) & 1] + L * 8;
#pragma unroll
            for (int tt = 0; tt < 8; ++tt) {
                short8 bf = ld16(w2p + tt * 512);
                acc2[0][tt] = mfma16(a20, bf, acc2[0][tt]);
                acc2[1][tt] = mfma16(a21, bf, acc2[1][tt]);
            }
            wave_lds_fence();   // WAR: chunk halves reused next pass-pair
        }

        rb = (rb == 2) ? 0 : rb + 1;
    }

    // ---- epilogue: segmented reduce over sorted dsts, atomics at run ends ----
    float* sRed = (float*)sW1;          // 24 KB >= 128*RSTR*4 B, dead after last pass
    int tcol = tid & 15;                // 0..15
    int row0 = (tid >> 4) * 8;          // chunk of 8 rows
#pragma unroll
    for (int tt = 0; tt < 8; ++tt) {
        __syncthreads();                // prior reads of sRed/sW1 done
        float bv = cb2[tt * 16 + m];
#pragma unroll
        for (int t = 0; t < 2; ++t)
#pragma unroll
            for (int r = 0; r < 4; ++r)
                sRed[(w * 32 + t * 16 + quad * 4 + r) * RSTR + m] =
                    silu_f(acc2[t][tt][r] + bv);
        __syncthreads();
        // 256 threads: 16 cols x 16 chunks of 8 rows; segmented scan per chunk
        float s = sRed[row0 * RSTR + tcol];
        int cd = sDst[row0];
        for (int i = 1; i < 8; ++i) {
            int rr = row0 + i;
            int d2 = sDst[rr];
            float v = sRed[rr * RSTR + tcol];
            if (d2 == cd) {
                s += v;
            } else {
                atomicAdd(aggr + (size_t)cd * HD + tt * 16 + tcol, s);
                cd = d2;
                s = v;
            }
        }
        atomicAdd(aggr + (size_t)cd * HD + tt * 16 + tcol, s);
    }
}

// ---------------- post: x = LN(x + aggr/cnt); emit bf16; re-zero aggr ----------------
__global__ __launch_bounds__(128) void k_post(
    float* __restrict__ aggr, const float* __restrict__ cnt,
    const float* __restrict__ g, const float* __restrict__ bet,
    float* __restrict__ x, ushort* __restrict__ x_bf)
{
    int node = blockIdx.x;
    int h = threadIdx.x;
    float inv = __builtin_amdgcn_rcpf(fmaxf(cnt[node], 1.0f));
    float av = aggr[(size_t)node * HD + h];
    aggr[(size_t)node * HD + h] = 0.0f;          // ready for next layer's atomics
    float acc = x[(size_t)node * HD + h] + av * inv;
    __shared__ float s1[2], s2[2];
    float sum = acc, sq = acc * acc;
    for (int off = 32; off > 0; off >>= 1) { sum += __shfl_down(sum, off); sq += __shfl_down(sq, off); }
    int wid = h >> 6, lane = h & 63;
    if (lane == 0) { s1[wid] = sum; s2[wid] = sq; }
    __syncthreads();
    float m = (s1[0] + s1[1]) * (1.0f / 128.0f);
    float v = (s2[0] + s2[1]) * (1.0f / 128.0f) - m * m;
    float y = (acc - m) * rsqrtf(v + LN_EPS) * g[h] + bet[h];
    x[(size_t)node * HD + h] = y;
    x_bf[(size_t)node * HD + h] = f2bf(y);
}

// ---------------- graph pooling ----------------
__global__ __launch_bounds__(128) void k_gaggr(
    const float* __restrict__ x, const int* __restrict__ bm,
    float* __restrict__ crystal)
{
    int node = blockIdx.x;
    int h = threadIdx.x;
    atomicAdd(&crystal[(size_t)bm[node] * HD + h], x[(size_t)node * HD + h]);
}

// ---------------- readout MLP ----------------
__global__ __launch_bounds__(128) void k_readout(
    const float* __restrict__ crystal, const float* __restrict__ gcnt,
    const float* __restrict__ w1, const float* __restrict__ b1,
    const float* __restrict__ w2, const float* __restrict__ b2,
    const float* __restrict__ w3, const float* __restrict__ b3,
    float* __restrict__ out)
{
    int gph = blockIdx.x;
    int t = threadIdx.x;
    __shared__ float sc[HD], sh1[HD], sh2[64];
    float inv = __builtin_amdgcn_rcpf(fmaxf(gcnt[gph], 1.0f));
    sc[t] = crystal[(size_t)gph * HD + t] * inv;
    __syncthreads();
    float acc = b1[t];
    for (int k = 0; k < HD; k++) acc += sc[k] * w1[k * HD + t];
    sh1[t] = silu_f(acc);
    __syncthreads();
    if (t < 64) {
        float a2 = b2[t];
        for (int k = 0; k < HD; k++) a2 += sh1[k] * w2[k * 64 + t];
        sh2[t] = silu_f(a2);
    }
    __syncthreads();
    if (t < NT) {
        float a3 = b3[t];
        for (int k = 0; k < 64; k++) a3 += sh2[k] * w3[k * NT + t];
        out[(size_t)gph * NT + t] = a3;
    }
}

extern "C" void kernel_launch(void* const* d_in, const int* in_sizes, int n_in,
                              void* d_out, int out_size, void* d_ws, size_t ws_size,
                              hipStream_t stream)
{
    const float* atom_fea = (const float*)d_in[0];
    const float* nbr_fea  = (const float*)d_in[1];
    const int*   nbr_idx  = (const int*)d_in[2];
    const int*   bm       = (const int*)d_in[3];
    const float* emb_w    = (const float*)d_in[4];
    const float* emb_b    = (const float*)d_in[5];
    const float* emb_ln_g = (const float*)d_in[6];
    const float* emb_ln_b = (const float*)d_in[7];
    const float* edge_w   = (const float*)d_in[8];
    const float* edge_b   = (const float*)d_in[9];
    const float* conv_w1  = (const float*)d_in[10];
    const float* conv_b1  = (const float*)d_in[11];
    const float* conv_w2  = (const float*)d_in[12];
    const float* conv_b2  = (const float*)d_in[13];
    const float* ln_g     = (const float*)d_in[14];
    const float* ln_b     = (const float*)d_in[15];
    const float* out_w1   = (const float*)d_in[16];
    const float* out_b1   = (const float*)d_in[17];
    const float* out_w2   = (const float*)d_in[18];
    const float* out_b2   = (const float*)d_in[19];
    const float* out_w3   = (const float*)d_in[20];
    const float* out_b3   = (const float*)d_in[21];
    float* out = (float*)d_out;

    // ---- workspace layout (256B-aligned regions) ----
    char* base = (char*)d_ws;
    size_t off = 0;
    auto alloc = [&](size_t bytes) -> char* {
        char* p = base + off;
        off = (off + bytes + 255) & ~(size_t)255;
        return p;
    };
    float*  xbuf    = (float*) alloc((size_t)N_NODES * HD * 4);
    float*  aggr    = (float*) alloc((size_t)N_NODES * HD * 4);
    float*  cnt     = (float*) alloc((size_t)N_NODES * 4);
    float*  crystal = (float*) alloc((size_t)N_GRAPHS * HD * 4);
    float*  gcnt    = (float*) alloc((size_t)N_GRAPHS * 4);
    ushort* x_bf    = (ushort*)alloc((size_t)N_NODES * HD * 2);
    ushort* e_bf    = (ushort*)alloc((size_t)N_EDGES * HD * 2);
    ushort* w1s     = (ushort*)alloc((size_t)NLAYERS * 65536 * 2);
    ushort* w2s     = (ushort*)alloc((size_t)NLAYERS * 32768 * 2);
    int*    cnt_i   = (int*)   alloc((size_t)N_NODES * 4);
    int*    cur     = (int*)   alloc((size_t)N_NODES * 4);
    int*    ssrc    = (int*)   alloc((size_t)N_EDGES * 4);
    int*    sdst    = (int*)   alloc((size_t)N_EDGES * 4);
    int*    posof   = (int*)   alloc((size_t)N_EDGES * 4);

    // weights -> swizzled bf16
    k_swz_w1<<<(NLAYERS * 65536) / 256, 256, 0, stream>>>(conv_w1, w1s);
    k_swz_w2<<<(NLAYERS * 32768) / 256, 256, 0, stream>>>(conv_w2, w2s);

    // zero aggr (layer 0 only; k_post re-zeroes for later layers)
    k_zero<<<(N_NODES * HD) / 256, 256, 0, stream>>>(aggr, N_NODES * HD);
    // zero cnt + crystal + gcnt (contiguous region) and cnt_i
    int zn = N_NODES + N_GRAPHS * HD + N_GRAPHS + 128;
    k_zero<<<(zn + 255) / 256, 256, 0, stream>>>(cnt, zn);
    k_zero<<<(N_NODES + 255) / 256, 256, 0, stream>>>((float*)cnt_i, N_NODES);

    // counting sort of edges by dst
    k_hist<<<N_EDGES / 256, 256, 0, stream>>>(nbr_idx, cnt_i);
    k_scan<<<1, 256, 0, stream>>>(cnt_i, cur, cnt);
    k_scatter<<<N_EDGES / 256, 256, 0, stream>>>(nbr_idx, cur, ssrc, sdst, posof);

    k_node_embed<<<N_NODES, 128, 0, stream>>>(atom_fea, emb_w, emb_b, emb_ln_g, emb_ln_b, xbuf, x_bf);
    k_edge_embed<<<N_EDGES / ETILE, 128, 0, stream>>>(nbr_fea, edge_w, edge_b, posof, e_bf);
    k_gcount<<<(N_NODES + 255) / 256, 256, 0, stream>>>(bm, gcnt);

    for (int l = 0; l < NLAYERS; ++l) {
        k_conv_mfma<<<N_EDGES / 128, 256, 0, stream>>>(
            x_bf, e_bf, ssrc, sdst,
            w1s + (size_t)l * 65536, conv_b1 + (size_t)l * 256,
            w2s + (size_t)l * 32768, conv_b2 + (size_t)l * 128,
            aggr);
        k_post<<<N_NODES, 128, 0, stream>>>(aggr, cnt, ln_g + (size_t)l * HD, ln_b + (size_t)l * HD, xbuf, x_bf);
    }

    k_gaggr<<<N_NODES, 128, 0, stream>>>(xbuf, bm, crystal);
    k_readout<<<N_GRAPHS, 128, 0, stream>>>(crystal, gcnt, out_w1, out_b1, out_w2, out_b2, out_w3, out_b3, out);
}

// Round 6
// 2332.583 us; speedup vs baseline: 1.7651x; 1.0112x over previous
//
#include <hip/hip_runtime.h>
#include <hip/hip_bf16.h>
#include <math.h>

#define N_NODES 50000
#define N_EDGES 800000
#define N_GRAPHS 1024
#define HD 128
#define NLAYERS 5
#define EDGE_IN 41
#define NT 3
#define LN_EPS 1e-5f

typedef unsigned int uint;
typedef unsigned short ushort;
typedef __attribute__((ext_vector_type(8))) short short8;
typedef __attribute__((ext_vector_type(4))) float f32x4;

// fast silu: x * rcp(1+exp(-x)); v_rcp_f32 rel err ~1e-7 (vs 6.8e-4 threshold)
__device__ __forceinline__ float silu_f(float v) {
    return v * __builtin_amdgcn_rcpf(1.0f + __expf(-v));
}

// round-to-nearest-even f32 -> bf16 bits
__device__ __forceinline__ ushort f2bf(float f) {
    uint u = __float_as_uint(f);
    u = u + 0x7FFFu + ((u >> 16) & 1u);
    return (ushort)(u >> 16);
}

__device__ __forceinline__ short8 ld16(const ushort* p) {
    union { int4 i; short8 s; } u;
    u.i = *(const int4*)p;
    return u.s;
}

__device__ __forceinline__ f32x4 mfma16(short8 a, short8 b, f32x4 c) {
    return __builtin_amdgcn_mfma_f32_16x16x32_bf16(a, b, c, 0, 0, 0);
}

// wave-local LDS fence
__device__ __forceinline__ void wave_lds_fence() {
    __asm__ volatile("s_waitcnt lgkmcnt(0)" ::: "memory");
}

// async global->LDS, 16 B per lane; HW writes lane's data to ldsbase + lane*16
__device__ __forceinline__ void cp16(const ushort* g, ushort* l) {
    __builtin_amdgcn_global_load_lds(
        (const __attribute__((address_space(1))) unsigned int*)g,
        (__attribute__((address_space(3))) unsigned int*)l, 16, 0, 0);
}

// stage 4096 ushorts (8 KB): wave w covers [w*1024, +1024), lane-contig 16 B
__device__ __forceinline__ void stage4k(ushort* lds, const ushort* g, int w, int L) {
#pragma unroll
    for (int i = 0; i < 2; ++i) {
        int f = w * 1024 + i * 512;
        cp16(g + f + L * 8, lds + f);
    }
}

// ---------------- zero ----------------
__global__ void k_zero(float* __restrict__ p, int n) {
    int i = blockIdx.x * 256 + threadIdx.x;
    if (i < n) p[i] = 0.0f;
}

// ---------------- counting sort of edges by dst ----------------
__global__ void k_hist(const int* __restrict__ nbr_idx, int* __restrict__ cnt_i) {
    int i = blockIdx.x * 256 + threadIdx.x;
    if (i < N_EDGES) atomicAdd(&cnt_i[nbr_idx[2 * i + 1]], 1);
}

// single-block exclusive scan over cnt_i -> cur (start offsets); also cnt float for k_post
__global__ __launch_bounds__(256) void k_scan(
    const int* __restrict__ cnt_i, int* __restrict__ cur, float* __restrict__ cntf)
{
    __shared__ int warpsum[4];
    __shared__ int srun;
    int tid = threadIdx.x;
    int lane = tid & 63, wv = tid >> 6;
    if (tid == 0) srun = 0;
    __syncthreads();
    for (int base = 0; base < N_NODES; base += 256) {
        int i = base + tid;
        int c = (i < N_NODES) ? cnt_i[i] : 0;
        int s = c;
        for (int off = 1; off < 64; off <<= 1) {
            int t = __shfl_up(s, off);
            if (lane >= off) s += t;
        }
        if (lane == 63) warpsum[wv] = s;
        __syncthreads();
        int woff = 0;
        for (int k = 0; k < wv; ++k) woff += warpsum[k];
        int run = srun;
        if (i < N_NODES) {
            cur[i]  = run + woff + s - c;
            cntf[i] = (float)c;
        }
        __syncthreads();
        if (tid == 255) srun = run + woff + s;
    }
}

// scatter edges into dst-sorted order
__global__ void k_scatter(const int* __restrict__ nbr_idx, int* __restrict__ cur,
                          int* __restrict__ ssrc, int* __restrict__ sdst,
                          int* __restrict__ posof)
{
    int e = blockIdx.x * 256 + threadIdx.x;
    if (e < N_EDGES) {
        int s = nbr_idx[2 * e];
        int d = nbr_idx[2 * e + 1];
        int p = atomicAdd(&cur[d], 1);
        ssrc[p] = s;
        sdst[p] = d;
        posof[e] = p;
    }
}

// ---------------- weight swizzle: 16x16x32 B-fragment order ----------------
__global__ void k_swz_w1(const float* __restrict__ w1, ushort* __restrict__ w1s) {
    int i = blockIdx.x * 256 + threadIdx.x;            // 5 * 65536
    int l = i >> 16;
    int r = i & 65535;
    int j = r & 7, L = (r >> 3) & 63, s = (r >> 9) & 7, c = (r >> 12) & 15;
    int k = 32 * s + ((L >> 4) & 3) * 8 + j;
    int n = 16 * c + (L & 15);
    w1s[i] = f2bf(w1[(size_t)l * 65536 + k * 256 + n]);
}
__global__ void k_swz_w2(const float* __restrict__ w2, ushort* __restrict__ w2s) {
    int i = blockIdx.x * 256 + threadIdx.x;            // 5 * 32768
    int l = i >> 15;
    int r = i & 32767;
    int j = r & 7, L = (r >> 3) & 63, t = (r >> 9) & 7, s2 = (r >> 12) & 7;
    int k = 32 * s2 + ((L >> 4) & 3) * 8 + j;
    int n = 16 * t + (L & 15);
    w2s[i] = f2bf(w2[(size_t)l * 32768 + k * 128 + n]);
}

// ---------------- node embed: x = silu(LN(atom @ emb_w + emb_b)) ----------------
__global__ __launch_bounds__(128) void k_node_embed(
    const float* __restrict__ atom, const float* __restrict__ w,
    const float* __restrict__ b, const float* __restrict__ g,
    const float* __restrict__ bet, float* __restrict__ x, ushort* __restrict__ x_bf)
{
    int node = blockIdx.x;
    int h = threadIdx.x;
    float4 a = *(const float4*)(atom + (size_t)node * 4);
    float acc = b[h] + a.x * w[h] + a.y * w[HD + h] + a.z * w[2 * HD + h] + a.w * w[3 * HD + h];
    __shared__ float s1[2], s2[2];
    float sum = acc, sq = acc * acc;
    for (int off = 32; off > 0; off >>= 1) { sum += __shfl_down(sum, off); sq += __shfl_down(sq, off); }
    int wid = h >> 6, lane = h & 63;
    if (lane == 0) { s1[wid] = sum; s2[wid] = sq; }
    __syncthreads();
    float m = (s1[0] + s1[1]) * (1.0f / 128.0f);
    float v = (s2[0] + s2[1]) * (1.0f / 128.0f) - m * m;
    float y = (acc - m) * rsqrtf(v + LN_EPS) * g[h] + bet[h];
    y = silu_f(y);
    x[(size_t)node * HD + h] = y;
    x_bf[(size_t)node * HD + h] = f2bf(y);
}

// ---------------- edge embed -> bf16, written in dst-sorted position ----------------
#define ETILE 32
__global__ __launch_bounds__(128) void k_edge_embed(
    const float* __restrict__ fea, const float* __restrict__ w,
    const float* __restrict__ b, const int* __restrict__ posof,
    ushort* __restrict__ e_bf)
{
    __shared__ float sf[ETILE][EDGE_IN + 1];
    int e0 = blockIdx.x * ETILE;
    int tid = threadIdx.x;
    for (int i = tid; i < ETILE * EDGE_IN; i += 128) {
        int m = i / EDGE_IN, k = i % EDGE_IN;
        sf[m][k] = fea[(size_t)(e0 + m) * EDGE_IN + k];
    }
    __syncthreads();
    float bb = b[tid];
    float acc[ETILE];
#pragma unroll
    for (int m = 0; m < ETILE; m++) acc[m] = bb;
    for (int k = 0; k < EDGE_IN; k++) {
        float wk = w[k * HD + tid];
#pragma unroll
        for (int m = 0; m < ETILE; m++) acc[m] += sf[m][k] * wk;
    }
#pragma unroll
    for (int m = 0; m < ETILE; m++) {
        int p = posof[e0 + m];
        e_bf[(size_t)p * HD + tid] = f2bf(silu_f(acc[m]));
    }
}

// ---------------- graph counts ----------------
__global__ void k_gcount(const int* __restrict__ bm, float* __restrict__ gcnt) {
    int i = blockIdx.x * 256 + threadIdx.x;
    if (i < N_NODES) atomicAdd(&gcnt[bm[i]], 1.0f);
}

// ---------------- fused conv layer over dst-sorted edges ----------------
// R6: R3's verified schedule (plain __syncthreads per pass), but W2
// SINGLE-buffered: chunk q staged at even pass 2q (prologue stages chunk 0),
// read only at odd pass 2q+1 -- the staged write lands under the next
// barrier's vmcnt(0) drain; the previous read of the buffer completed before
// the pass-2q barrier. LDS 43.5 -> 35.3 KB => 4 blocks/CU (4 waves/SIMD).
// Register budget stays at launch_bounds(256,3) (cap 170 VGPR) -- R4 proved
// (256,4)'s 128-reg cap spills to scratch (FETCH 855 MB, 2x slower).
// Epilogue: segmented reduction over dst-sorted edges (stride-18 sRed: both
// write (72B) and read (144B) patterns are 2-way bank-aliased = free).
#define M1CP 40
#define RSTR 18
__global__ __launch_bounds__(256, 3) void k_conv_mfma(
    const ushort* __restrict__ x_bf, const ushort* __restrict__ e_bf,
    const int* __restrict__ ssrc, const int* __restrict__ sdst,
    const ushort* __restrict__ w1s, const float* __restrict__ cb1,
    const ushort* __restrict__ w2s, const float* __restrict__ cb2,
    float* __restrict__ aggr)
{
    __shared__ __align__(16) ushort sW1[2][4096];
    __shared__ __align__(16) ushort sW2[4096];
    __shared__ __align__(16) ushort sM1[4][32 * M1CP];
    __shared__ int sDst[128];

    int tid = threadIdx.x;
    int w = tid >> 6;
    int L = tid & 63;
    int m = L & 15;          // row/col-in-tile selector
    int quad = L >> 4;       // 0..3
    int eb = blockIdx.x * 128;
    int ew = eb + w * 32;    // wave's 32 edges

    if (tid < 128) sDst[tid] = sdst[eb + tid];

    // A-fragments loaded once: tile t edges ew + t*16 + m
    short8 af[2][8];
#pragma unroll
    for (int t = 0; t < 2; ++t) {
        int src = ssrc[ew + t * 16 + m];
        const ushort* xr = x_bf + (size_t)src * HD + quad * 8;
        const ushort* er = e_bf + (size_t)(ew + t * 16 + m) * HD + quad * 8;
#pragma unroll
        for (int s = 0; s < 4; ++s) af[t][s] = ld16(xr + 32 * s);
#pragma unroll
        for (int s = 0; s < 4; ++s) af[t][4 + s] = ld16(er + 32 * s);
    }

    f32x4 acc2[2][8];
#pragma unroll
    for (int t = 0; t < 2; ++t)
#pragma unroll
        for (int tt = 0; tt < 8; ++tt)
#pragma unroll
            for (int r = 0; r < 4; ++r) acc2[t][tt][r] = 0.0f;

    ushort* sm = sM1[w];

    // prologue: stage pass-0 W1 chunk and s2=0 W2 chunk
    stage4k(sW1[0], w1s, w, L);
    stage4k(sW2, w2s, w, L);

    for (int p = 0; p < 16; ++p) {
        __syncthreads();   // drains vmcnt -> current buffers ready
        // prefetch (overlaps compute below)
        if (p < 15) stage4k(sW1[(p + 1) & 1], w1s + (p + 1) * 4096, w, L);
        if (!(p & 1) && p >= 2)                       // stage W2 chunk p/2 (1..7)
            stage4k(sW2, w2s + (p >> 1) * 4096, w, L);

        // ---- GEMM1: cols [p*16, +16), both M-tiles share each B-frag ----
        f32x4 p0, p1;
#pragma unroll
        for (int r = 0; r < 4; ++r) { p0[r] = 0.0f; p1[r] = 0.0f; }
        const ushort* wb = sW1[p & 1] + L * 8;
#pragma unroll
        for (int s = 0; s < 8; ++s) {
            short8 wv = ld16(wb + s * 512);
            p0 = mfma16(af[0][s], wv, p0);
            p1 = mfma16(af[1][s], wv, p1);
        }

        // ---- bias + silu -> bf16 half-chunk (col = (p&1)*16 + m) ----
        float bv = cb1[p * 16 + m];
        int hb = (p & 1) * 16;
#pragma unroll
        for (int r = 0; r < 4; ++r) {
            sm[(quad * 4 + r) * M1CP + hb + m]        = f2bf(silu_f(p0[r] + bv));
            sm[(16 + quad * 4 + r) * M1CP + hb + m]   = f2bf(silu_f(p1[r] + bv));
        }

        // ---- odd pass: GEMM2 k-step s2 = p>>1 over the 32-col chunk ----
        if (p & 1) {
            wave_lds_fence();   // m1 writes (this+prev pass) complete
            short8 a20 = ld16(sm + m * M1CP + quad * 8);
            short8 a21 = ld16(sm + (16 + m) * M1CP + quad * 8);
            const ushort* w2p = sW2 + L * 8;
#pragma unroll
            for (int tt = 0; tt < 8; ++tt) {
                short8 bf = ld16(w2p + tt * 512);
                acc2[0][tt] = mfma16(a20, bf, acc2[0][tt]);
                acc2[1][tt] = mfma16(a21, bf, acc2[1][tt]);
            }
            wave_lds_fence();   // WAR: chunk halves reused next pass-pair
        }
    }

    // ---- epilogue: segmented reduce over sorted dsts, atomics at run ends ----
    float* sRed = (float*)sW1;          // 16 KB >= 128*RSTR*4 B, dead after last pass
    int tcol = tid & 15;                // 0..15
    int row0 = (tid >> 4) * 8;          // chunk of 8 rows
#pragma unroll
    for (int tt = 0; tt < 8; ++tt) {
        __syncthreads();                // prior reads of sRed/sW1 done
        float bv = cb2[tt * 16 + m];
#pragma unroll
        for (int t = 0; t < 2; ++t)
#pragma unroll
            for (int r = 0; r < 4; ++r)
                sRed[(w * 32 + t * 16 + quad * 4 + r) * RSTR + m] =
                    silu_f(acc2[t][tt][r] + bv);
        __syncthreads();
        // 256 threads: 16 cols x 16 chunks of 8 rows; segmented scan per chunk
        float s = sRed[row0 * RSTR + tcol];
        int cd = sDst[row0];
        for (int i = 1; i < 8; ++i) {
            int rr = row0 + i;
            int d2 = sDst[rr];
            float v = sRed[rr * RSTR + tcol];
            if (d2 == cd) {
                s += v;
            } else {
                atomicAdd(aggr + (size_t)cd * HD + tt * 16 + tcol, s);
                cd = d2;
                s = v;
            }
        }
        atomicAdd(aggr + (size_t)cd * HD + tt * 16 + tcol, s);
    }
}

// ---------------- post: x = LN(x + aggr/cnt); emit bf16; re-zero aggr ----------------
__global__ __launch_bounds__(128) void k_post(
    float* __restrict__ aggr, const float* __restrict__ cnt,
    const float* __restrict__ g, const float* __restrict__ bet,
    float* __restrict__ x, ushort* __restrict__ x_bf)
{
    int node = blockIdx.x;
    int h = threadIdx.x;
    float inv = __builtin_amdgcn_rcpf(fmaxf(cnt[node], 1.0f));
    float av = aggr[(size_t)node * HD + h];
    aggr[(size_t)node * HD + h] = 0.0f;          // ready for next layer's atomics
    float acc = x[(size_t)node * HD + h] + av * inv;
    __shared__ float s1[2], s2[2];
    float sum = acc, sq = acc * acc;
    for (int off = 32; off > 0; off >>= 1) { sum += __shfl_down(sum, off); sq += __shfl_down(sq, off); }
    int wid = h >> 6, lane = h & 63;
    if (lane == 0) { s1[wid] = sum; s2[wid] = sq; }
    __syncthreads();
    float m = (s1[0] + s1[1]) * (1.0f / 128.0f);
    float v = (s2[0] + s2[1]) * (1.0f / 128.0f) - m * m;
    float y = (acc - m) * rsqrtf(v + LN_EPS) * g[h] + bet[h];
    x[(size_t)node * HD + h] = y;
    x_bf[(size_t)node * HD + h] = f2bf(y);
}

// ---------------- graph pooling ----------------
__global__ __launch_bounds__(128) void k_gaggr(
    const float* __restrict__ x, const int* __restrict__ bm,
    float* __restrict__ crystal)
{
    int node = blockIdx.x;
    int h = threadIdx.x;
    atomicAdd(&crystal[(size_t)bm[node] * HD + h], x[(size_t)node * HD + h]);
}

// ---------------- readout MLP ----------------
__global__ __launch_bounds__(128) void k_readout(
    const float* __restrict__ crystal, const float* __restrict__ gcnt,
    const float* __restrict__ w1, const float* __restrict__ b1,
    const float* __restrict__ w2, const float* __restrict__ b2,
    const float* __restrict__ w3, const float* __restrict__ b3,
    float* __restrict__ out)
{
    int gph = blockIdx.x;
    int t = threadIdx.x;
    __shared__ float sc[HD], sh1[HD], sh2[64];
    float inv = __builtin_amdgcn_rcpf(fmaxf(gcnt[gph], 1.0f));
    sc[t] = crystal[(size_t)gph * HD + t] * inv;
    __syncthreads();
    float acc = b1[t];
    for (int k = 0; k < HD; k++) acc += sc[k] * w1[k * HD + t];
    sh1[t] = silu_f(acc);
    __syncthreads();
    if (t < 64) {
        float a2 = b2[t];
        for (int k = 0; k < HD; k++) a2 += sh1[k] * w2[k * 64 + t];
        sh2[t] = silu_f(a2);
    }
    __syncthreads();
    if (t < NT) {
        float a3 = b3[t];
        for (int k = 0; k < 64; k++) a3 += sh2[k] * w3[k * NT + t];
        out[(size_t)gph * NT + t] = a3;
    }
}

extern "C" void kernel_launch(void* const* d_in, const int* in_sizes, int n_in,
                              void* d_out, int out_size, void* d_ws, size_t ws_size,
                              hipStream_t stream)
{
    const float* atom_fea = (const float*)d_in[0];
    const float* nbr_fea  = (const float*)d_in[1];
    const int*   nbr_idx  = (const int*)d_in[2];
    const int*   bm       = (const int*)d_in[3];
    const float* emb_w    = (const float*)d_in[4];
    const float* emb_b    = (const float*)d_in[5];
    const float* emb_ln_g = (const float*)d_in[6];
    const float* emb_ln_b = (const float*)d_in[7];
    const float* edge_w   = (const float*)d_in[8];
    const float* edge_b   = (const float*)d_in[9];
    const float* conv_w1  = (const float*)d_in[10];
    const float* conv_b1  = (const float*)d_in[11];
    const float* conv_w2  = (const float*)d_in[12];
    const float* conv_b2  = (const float*)d_in[13];
    const float* ln_g     = (const float*)d_in[14];
    const float* ln_b     = (const float*)d_in[15];
    const float* out_w1   = (const float*)d_in[16];
    const float* out_b1   = (const float*)d_in[17];
    const float* out_w2   = (const float*)d_in[18];
    const float* out_b2   = (const float*)d_in[19];
    const float* out_w3   = (const float*)d_in[20];
    const float* out_b3   = (const float*)d_in[21];
    float* out = (float*)d_out;

    // ---- workspace layout (256B-aligned regions) ----
    char* base = (char*)d_ws;
    size_t off = 0;
    auto alloc = [&](size_t bytes) -> char* {
        char* p = base + off;
        off = (off + bytes + 255) & ~(size_t)255;
        return p;
    };
    float*  xbuf    = (float*) alloc((size_t)N_NODES * HD * 4);
    float*  aggr    = (float*) alloc((size_t)N_NODES * HD * 4);
    float*  cnt     = (float*) alloc((size_t)N_NODES * 4);
    float*  crystal = (float*) alloc((size_t)N_GRAPHS * HD * 4);
    float*  gcnt    = (float*) alloc((size_t)N_GRAPHS * 4);
    ushort* x_bf    = (ushort*)alloc((size_t)N_NODES * HD * 2);
    ushort* e_bf    = (ushort*)alloc((size_t)N_EDGES * HD * 2);
    ushort* w1s     = (ushort*)alloc((size_t)NLAYERS * 65536 * 2);
    ushort* w2s     = (ushort*)alloc((size_t)NLAYERS * 32768 * 2);
    int*    cnt_i   = (int*)   alloc((size_t)N_NODES * 4);
    int*    cur     = (int*)   alloc((size_t)N_NODES * 4);
    int*    ssrc    = (int*)   alloc((size_t)N_EDGES * 4);
    int*    sdst    = (int*)   alloc((size_t)N_EDGES * 4);
    int*    posof   = (int*)   alloc((size_t)N_EDGES * 4);

    // weights -> swizzled bf16
    k_swz_w1<<<(NLAYERS * 65536) / 256, 256, 0, stream>>>(conv_w1, w1s);
    k_swz_w2<<<(NLAYERS * 32768) / 256, 256, 0, stream>>>(conv_w2, w2s);

    // zero aggr (layer 0 only; k_post re-zeroes for later layers)
    k_zero<<<(N_NODES * HD) / 256, 256, 0, stream>>>(aggr, N_NODES * HD);
    // zero cnt + crystal + gcnt (contiguous region) and cnt_i
    int zn = N_NODES + N_GRAPHS * HD + N_GRAPHS + 128;
    k_zero<<<(zn + 255) / 256, 256, 0, stream>>>(cnt, zn);
    k_zero<<<(N_NODES + 255) / 256, 256, 0, stream>>>((float*)cnt_i, N_NODES);

    // counting sort of edges by dst
    k_hist<<<N_EDGES / 256, 256, 0, stream>>>(nbr_idx, cnt_i);
    k_scan<<<1, 256, 0, stream>>>(cnt_i, cur, cnt);
    k_scatter<<<N_EDGES / 256, 256, 0, stream>>>(nbr_idx, cur, ssrc, sdst, posof);

    k_node_embed<<<N_NODES, 128, 0, stream>>>(atom_fea, emb_w, emb_b, emb_ln_g, emb_ln_b, xbuf, x_bf);
    k_edge_embed<<<N_EDGES / ETILE, 128, 0, stream>>>(nbr_fea, edge_w, edge_b, posof, e_bf);
    k_gcount<<<(N_NODES + 255) / 256, 256, 0, stream>>>(bm, gcnt);

    for (int l = 0; l < NLAYERS; ++l) {
        k_conv_mfma<<<N_EDGES / 128, 256, 0, stream>>>(
            x_bf, e_bf, ssrc, sdst,
            w1s + (size_t)l * 65536, conv_b1 + (size_t)l * 256,
            w2s + (size_t)l * 32768, conv_b2 + (size_t)l * 128,
            aggr);
        k_post<<<N_NODES, 128, 0, stream>>>(aggr, cnt, ln_g + (size_t)l * HD, ln_b + (size_t)l * HD, xbuf, x_bf);
    }

    k_gaggr<<<N_NODES, 128, 0, stream>>>(xbuf, bm, crystal);
    k_readout<<<N_GRAPHS, 128, 0, stream>>>(crystal, gcnt, out_w1, out_b1, out_w2, out_b2, out_w3, out_b3, out);
}

// Round 7
// 2251.206 us; speedup vs baseline: 1.8289x; 1.0361x over previous
//
#include <hip/hip_runtime.h>
#include <hip/hip_bf16.h>
#include <math.h>

#define N_NODES 50000
#define N_EDGES 800000
#define N_GRAPHS 1024
#define HD 128
#define NLAYERS 5
#define EDGE_IN 41
#define NT 3
#define LN_EPS 1e-5f

typedef unsigned int uint;
typedef unsigned short ushort;
typedef __attribute__((ext_vector_type(8))) short short8;
typedef __attribute__((ext_vector_type(4))) float f32x4;
typedef __attribute__((ext_vector_type(4))) ushort us4;

// fast silu: x * rcp(1+exp(-x)); v_rcp_f32 rel err ~1e-7 (vs 6.8e-4 threshold)
__device__ __forceinline__ float silu_f(float v) {
    return v * __builtin_amdgcn_rcpf(1.0f + __expf(-v));
}

// round-to-nearest-even f32 -> bf16 bits
__device__ __forceinline__ ushort f2bf(float f) {
    uint u = __float_as_uint(f);
    u = u + 0x7FFFu + ((u >> 16) & 1u);
    return (ushort)(u >> 16);
}

__device__ __forceinline__ short8 ld16(const ushort* p) {
    union { int4 i; short8 s; } u;
    u.i = *(const int4*)p;
    return u.s;
}

__device__ __forceinline__ f32x4 mfma16(short8 a, short8 b, f32x4 c) {
    return __builtin_amdgcn_mfma_f32_16x16x32_bf16(a, b, c, 0, 0, 0);
}

// compiler-only reorder barrier (no HW wait): stops TBAA moving the int4-cast
// LDS reads across the ushort LDS writes; HW same-wave DS ops are in-order.
__device__ __forceinline__ void compiler_fence() {
    __asm__ volatile("" ::: "memory");
}

// async global->LDS, 16 B per lane; HW writes lane's data to ldsbase + lane*16
__device__ __forceinline__ void cp16(const ushort* g, ushort* l) {
    __builtin_amdgcn_global_load_lds(
        (const __attribute__((address_space(1))) unsigned int*)g,
        (__attribute__((address_space(3))) unsigned int*)l, 16, 0, 0);
}

// stage 4096 ushorts (8 KB): wave w covers [w*1024, +1024), lane-contig 16 B
__device__ __forceinline__ void stage4k(ushort* lds, const ushort* g, int w, int L) {
#pragma unroll
    for (int i = 0; i < 2; ++i) {
        int f = w * 1024 + i * 512;
        cp16(g + f + L * 8, lds + f);
    }
}

// ---------------- zero ----------------
__global__ void k_zero(float* __restrict__ p, int n) {
    int i = blockIdx.x * 256 + threadIdx.x;
    if (i < n) p[i] = 0.0f;
}

// ---------------- counting sort of edges by dst ----------------
__global__ void k_hist(const int* __restrict__ nbr_idx, int* __restrict__ cnt_i) {
    int i = blockIdx.x * 256 + threadIdx.x;
    if (i < N_EDGES) atomicAdd(&cnt_i[nbr_idx[2 * i + 1]], 1);
}

// single-block exclusive scan over cnt_i -> cur (start offsets); also cnt float for k_post
__global__ __launch_bounds__(1024) void k_scan(
    const int* __restrict__ cnt_i, int* __restrict__ cur, float* __restrict__ cntf)
{
    __shared__ int warpsum[16];
    __shared__ int srun;
    int tid = threadIdx.x;
    int lane = tid & 63, wv = tid >> 6;
    if (tid == 0) srun = 0;
    __syncthreads();
    for (int base = 0; base < N_NODES; base += 1024) {
        int i = base + tid;
        int c = (i < N_NODES) ? cnt_i[i] : 0;
        int s = c;
        for (int off = 1; off < 64; off <<= 1) {
            int t = __shfl_up(s, off);
            if (lane >= off) s += t;
        }
        if (lane == 63) warpsum[wv] = s;
        __syncthreads();
        int woff = 0;
        for (int k = 0; k < wv; ++k) woff += warpsum[k];
        int run = srun;
        if (i < N_NODES) {
            cur[i]  = run + woff + s - c;
            cntf[i] = (float)c;
        }
        __syncthreads();
        if (tid == 1023) srun = run + woff + s;
    }
}

// scatter edges into dst-sorted order
__global__ void k_scatter(const int* __restrict__ nbr_idx, int* __restrict__ cur,
                          int* __restrict__ ssrc, int* __restrict__ sdst,
                          int* __restrict__ posof)
{
    int e = blockIdx.x * 256 + threadIdx.x;
    if (e < N_EDGES) {
        int s = nbr_idx[2 * e];
        int d = nbr_idx[2 * e + 1];
        int p = atomicAdd(&cur[d], 1);
        ssrc[p] = s;
        sdst[p] = d;
        posof[e] = p;
    }
}

// ---------------- weight swizzle: 16x16x32 B-fragment order ----------------
__global__ void k_swz_w1(const float* __restrict__ w1, ushort* __restrict__ w1s) {
    int i = blockIdx.x * 256 + threadIdx.x;            // 5 * 65536
    int l = i >> 16;
    int r = i & 65535;
    int j = r & 7, L = (r >> 3) & 63, s = (r >> 9) & 7, c = (r >> 12) & 15;
    int k = 32 * s + ((L >> 4) & 3) * 8 + j;
    int n = 16 * c + (L & 15);
    w1s[i] = f2bf(w1[(size_t)l * 65536 + k * 256 + n]);
}
__global__ void k_swz_w2(const float* __restrict__ w2, ushort* __restrict__ w2s) {
    int i = blockIdx.x * 256 + threadIdx.x;            // 5 * 32768
    int l = i >> 15;
    int r = i & 32767;
    int j = r & 7, L = (r >> 3) & 63, t = (r >> 9) & 7, s2 = (r >> 12) & 7;
    int k = 32 * s2 + ((L >> 4) & 3) * 8 + j;
    int n = 16 * t + (L & 15);
    w2s[i] = f2bf(w2[(size_t)l * 32768 + k * 128 + n]);
}

// ---------------- node embed: x = silu(LN(atom @ emb_w + emb_b)) ----------------
__global__ __launch_bounds__(128) void k_node_embed(
    const float* __restrict__ atom, const float* __restrict__ w,
    const float* __restrict__ b, const float* __restrict__ g,
    const float* __restrict__ bet, float* __restrict__ x, ushort* __restrict__ x_bf)
{
    int node = blockIdx.x;
    int h = threadIdx.x;
    float4 a = *(const float4*)(atom + (size_t)node * 4);
    float acc = b[h] + a.x * w[h] + a.y * w[HD + h] + a.z * w[2 * HD + h] + a.w * w[3 * HD + h];
    __shared__ float s1[2], s2[2];
    float sum = acc, sq = acc * acc;
    for (int off = 32; off > 0; off >>= 1) { sum += __shfl_down(sum, off); sq += __shfl_down(sq, off); }
    int wid = h >> 6, lane = h & 63;
    if (lane == 0) { s1[wid] = sum; s2[wid] = sq; }
    __syncthreads();
    float m = (s1[0] + s1[1]) * (1.0f / 128.0f);
    float v = (s2[0] + s2[1]) * (1.0f / 128.0f) - m * m;
    float y = (acc - m) * rsqrtf(v + LN_EPS) * g[h] + bet[h];
    y = silu_f(y);
    x[(size_t)node * HD + h] = y;
    x_bf[(size_t)node * HD + h] = f2bf(y);
}

// ---------------- edge embed -> bf16, written in dst-sorted position ----------------
#define ETILE 32
__global__ __launch_bounds__(128) void k_edge_embed(
    const float* __restrict__ fea, const float* __restrict__ w,
    const float* __restrict__ b, const int* __restrict__ posof,
    ushort* __restrict__ e_bf)
{
    __shared__ float sf[ETILE][EDGE_IN + 1];
    int e0 = blockIdx.x * ETILE;
    int tid = threadIdx.x;
    for (int i = tid; i < ETILE * EDGE_IN; i += 128) {
        int m = i / EDGE_IN, k = i % EDGE_IN;
        sf[m][k] = fea[(size_t)(e0 + m) * EDGE_IN + k];
    }
    __syncthreads();
    float bb = b[tid];
    float acc[ETILE];
#pragma unroll
    for (int m = 0; m < ETILE; m++) acc[m] = bb;
    for (int k = 0; k < EDGE_IN; k++) {
        float wk = w[k * HD + tid];
#pragma unroll
        for (int m = 0; m < ETILE; m++) acc[m] += sf[m][k] * wk;
    }
#pragma unroll
    for (int m = 0; m < ETILE; m++) {
        int p = posof[e0 + m];
        e_bf[(size_t)p * HD + tid] = f2bf(silu_f(acc[m]));
    }
}

// ---------------- graph counts ----------------
__global__ void k_gcount(const int* __restrict__ bm, float* __restrict__ gcnt) {
    int i = blockIdx.x * 256 + threadIdx.x;
    if (i < N_NODES) atomicAdd(&gcnt[bm[i]], 1.0f);
}

// ---------------- fused conv layer over dst-sorted edges ----------------
// R7: R6 structure (W1 dbuf, W2 single-buffer, 35.3 KB LDS) with per-wave ILP:
//  - asm lgkmcnt(0) fences -> pure compiler barriers (sM1 is wave-private;
//    HW same-wave DS in-order; __syncthreads covers the cross-pass WAR).
//  - GEMM1 split into 4 independent MFMA chains (depth 8 -> 4) + 8 adds.
//  - s_setprio(1) around MFMA clusters (co-resident blocks are phase-diverse).
// Occupancy is unified-VGPR-bound at 3 waves/SIMD (~150 regs/wave) -- R4/R6
// proved LDS is not the limiter and (256,4) spills; keep (256,3).
#define M1CP 40
#define RSTR 18
__global__ __launch_bounds__(256, 3) void k_conv_mfma(
    const ushort* __restrict__ x_bf, const ushort* __restrict__ e_bf,
    const int* __restrict__ ssrc, const int* __restrict__ sdst,
    const ushort* __restrict__ w1s, const float* __restrict__ cb1,
    const ushort* __restrict__ w2s, const float* __restrict__ cb2,
    float* __restrict__ aggr)
{
    __shared__ __align__(16) ushort sW1[2][4096];
    __shared__ __align__(16) ushort sW2[4096];
    __shared__ __align__(16) ushort sM1[4][32 * M1CP];
    __shared__ int sDst[128];

    int tid = threadIdx.x;
    int w = tid >> 6;
    int L = tid & 63;
    int m = L & 15;          // row/col-in-tile selector
    int quad = L >> 4;       // 0..3
    int eb = blockIdx.x * 128;
    int ew = eb + w * 32;    // wave's 32 edges

    if (tid < 128) sDst[tid] = sdst[eb + tid];

    // A-fragments loaded once: tile t edges ew + t*16 + m
    short8 af[2][8];
#pragma unroll
    for (int t = 0; t < 2; ++t) {
        int src = ssrc[ew + t * 16 + m];
        const ushort* xr = x_bf + (size_t)src * HD + quad * 8;
        const ushort* er = e_bf + (size_t)(ew + t * 16 + m) * HD + quad * 8;
#pragma unroll
        for (int s = 0; s < 4; ++s) af[t][s] = ld16(xr + 32 * s);
#pragma unroll
        for (int s = 0; s < 4; ++s) af[t][4 + s] = ld16(er + 32 * s);
    }

    f32x4 acc2[2][8];
#pragma unroll
    for (int t = 0; t < 2; ++t)
#pragma unroll
        for (int tt = 0; tt < 8; ++tt)
#pragma unroll
            for (int r = 0; r < 4; ++r) acc2[t][tt][r] = 0.0f;

    ushort* sm = sM1[w];

    // prologue: stage pass-0 W1 chunk and s2=0 W2 chunk
    stage4k(sW1[0], w1s, w, L);
    stage4k(sW2, w2s, w, L);

    for (int p = 0; p < 16; ++p) {
        __syncthreads();   // drains vmcnt -> current buffers ready
        // prefetch (overlaps compute below)
        if (p < 15) stage4k(sW1[(p + 1) & 1], w1s + (p + 1) * 4096, w, L);
        if (!(p & 1) && p >= 2)                       // stage W2 chunk p/2 (1..7)
            stage4k(sW2, w2s + (p >> 1) * 4096, w, L);

        // ---- GEMM1: cols [p*16, +16); 4 independent MFMA chains ----
        f32x4 p0a, p0b, p1a, p1b;
#pragma unroll
        for (int r = 0; r < 4; ++r) { p0a[r] = 0.0f; p0b[r] = 0.0f; p1a[r] = 0.0f; p1b[r] = 0.0f; }
        const ushort* wb = sW1[p & 1] + L * 8;
        __builtin_amdgcn_s_setprio(1);
#pragma unroll
        for (int s = 0; s < 4; ++s) {
            short8 wv = ld16(wb + s * 512);
            p0a = mfma16(af[0][s], wv, p0a);
            p1a = mfma16(af[1][s], wv, p1a);
        }
#pragma unroll
        for (int s = 4; s < 8; ++s) {
            short8 wv = ld16(wb + s * 512);
            p0b = mfma16(af[0][s], wv, p0b);
            p1b = mfma16(af[1][s], wv, p1b);
        }
        __builtin_amdgcn_s_setprio(0);
        f32x4 p0 = p0a + p0b;
        f32x4 p1 = p1a + p1b;

        // ---- bias + silu -> bf16 half-chunk (col = (p&1)*16 + m) ----
        float bv = cb1[p * 16 + m];
        int hb = (p & 1) * 16;
#pragma unroll
        for (int r = 0; r < 4; ++r) {
            sm[(quad * 4 + r) * M1CP + hb + m]        = f2bf(silu_f(p0[r] + bv));
            sm[(16 + quad * 4 + r) * M1CP + hb + m]   = f2bf(silu_f(p1[r] + bv));
        }

        // ---- odd pass: GEMM2 k-step s2 = p>>1 over the 32-col chunk ----
        if (p & 1) {
            compiler_fence();   // keep program order of sm writes vs int4 reads
            short8 a20 = ld16(sm + m * M1CP + quad * 8);
            short8 a21 = ld16(sm + (16 + m) * M1CP + quad * 8);
            const ushort* w2p = sW2 + L * 8;
            __builtin_amdgcn_s_setprio(1);
#pragma unroll
            for (int tt = 0; tt < 8; ++tt) {
                short8 bf = ld16(w2p + tt * 512);
                acc2[0][tt] = mfma16(a20, bf, acc2[0][tt]);
                acc2[1][tt] = mfma16(a21, bf, acc2[1][tt]);
            }
            __builtin_amdgcn_s_setprio(0);
            compiler_fence();   // WAR vs next pass's sm writes (HW in-order)
        }
    }

    // ---- epilogue: segmented reduce over sorted dsts, atomics at run ends ----
    float* sRed = (float*)sW1;          // 16 KB >= 128*RSTR*4 B, dead after last pass
    int tcol = tid & 15;                // 0..15
    int row0 = (tid >> 4) * 8;          // chunk of 8 rows
#pragma unroll
    for (int tt = 0; tt < 8; ++tt) {
        __syncthreads();                // prior reads of sRed/sW1 done
        float bv = cb2[tt * 16 + m];
#pragma unroll
        for (int t = 0; t < 2; ++t)
#pragma unroll
            for (int r = 0; r < 4; ++r)
                sRed[(w * 32 + t * 16 + quad * 4 + r) * RSTR + m] =
                    silu_f(acc2[t][tt][r] + bv);
        __syncthreads();
        // 256 threads: 16 cols x 16 chunks of 8 rows; segmented scan per chunk
        float s = sRed[row0 * RSTR + tcol];
        int cd = sDst[row0];
        for (int i = 1; i < 8; ++i) {
            int rr = row0 + i;
            int d2 = sDst[rr];
            float v = sRed[rr * RSTR + tcol];
            if (d2 == cd) {
                s += v;
            } else {
                atomicAdd(aggr + (size_t)cd * HD + tt * 16 + tcol, s);
                cd = d2;
                s = v;
            }
        }
        atomicAdd(aggr + (size_t)cd * HD + tt * 16 + tcol, s);
    }
}

// ---------------- post: x = LN(x + aggr/cnt); emit bf16; re-zero aggr ----------------
// R7: 8 nodes per 256-thread block, float4 per thread, width-32 shfl reduce,
// no LDS, no barriers. 6250 blocks.
__global__ __launch_bounds__(256) void k_post(
    float* __restrict__ aggr, const float* __restrict__ cnt,
    const float* __restrict__ g, const float* __restrict__ bet,
    float* __restrict__ x, ushort* __restrict__ x_bf)
{
    int t = threadIdx.x;
    int node = blockIdx.x * 8 + (t >> 5);
    int c = (t & 31) * 4;
    size_t base = (size_t)node * HD + c;
    float inv = __builtin_amdgcn_rcpf(fmaxf(cnt[node], 1.0f));
    f32x4 av = *(f32x4*)(aggr + base);
    f32x4 z; z[0] = 0.0f; z[1] = 0.0f; z[2] = 0.0f; z[3] = 0.0f;
    *(f32x4*)(aggr + base) = z;               // ready for next layer's atomics
    f32x4 xv = *(const f32x4*)(x + base);
    f32x4 acc;
#pragma unroll
    for (int j = 0; j < 4; ++j) acc[j] = xv[j] + av[j] * inv;
    float sum = acc[0] + acc[1] + acc[2] + acc[3];
    float sq  = acc[0]*acc[0] + acc[1]*acc[1] + acc[2]*acc[2] + acc[3]*acc[3];
    for (int off = 16; off > 0; off >>= 1) {
        sum += __shfl_down(sum, off, 32);
        sq  += __shfl_down(sq,  off, 32);
    }
    float msum = __shfl(sum, 0, 32);
    float msq  = __shfl(sq,  0, 32);
    float mean = msum * (1.0f / 128.0f);
    float var  = msq * (1.0f / 128.0f) - mean * mean;
    float rstd = rsqrtf(var + LN_EPS);
    f32x4 gv = *(const f32x4*)(g + c);
    f32x4 bv = *(const f32x4*)(bet + c);
    f32x4 y;
    us4 ybf;
#pragma unroll
    for (int j = 0; j < 4; ++j) {
        y[j] = (acc[j] - mean) * rstd * gv[j] + bv[j];
        ybf[j] = f2bf(y[j]);
    }
    *(f32x4*)(x + base) = y;
    *(us4*)(x_bf + base) = ybf;
}

// ---------------- graph pooling ----------------
__global__ __launch_bounds__(128) void k_gaggr(
    const float* __restrict__ x, const int* __restrict__ bm,
    float* __restrict__ crystal)
{
    int node = blockIdx.x;
    int h = threadIdx.x;
    atomicAdd(&crystal[(size_t)bm[node] * HD + h], x[(size_t)node * HD + h]);
}

// ---------------- readout MLP ----------------
__global__ __launch_bounds__(128) void k_readout(
    const float* __restrict__ crystal, const float* __restrict__ gcnt,
    const float* __restrict__ w1, const float* __restrict__ b1,
    const float* __restrict__ w2, const float* __restrict__ b2,
    const float* __restrict__ w3, const float* __restrict__ b3,
    float* __restrict__ out)
{
    int gph = blockIdx.x;
    int t = threadIdx.x;
    __shared__ float sc[HD], sh1[HD], sh2[64];
    float inv = __builtin_amdgcn_rcpf(fmaxf(gcnt[gph], 1.0f));
    sc[t] = crystal[(size_t)gph * HD + t] * inv;
    __syncthreads();
    float acc = b1[t];
    for (int k = 0; k < HD; k++) acc += sc[k] * w1[k * HD + t];
    sh1[t] = silu_f(acc);
    __syncthreads();
    if (t < 64) {
        float a2 = b2[t];
        for (int k = 0; k < HD; k++) a2 += sh1[k] * w2[k * 64 + t];
        sh2[t] = silu_f(a2);
    }
    __syncthreads();
    if (t < NT) {
        float a3 = b3[t];
        for (int k = 0; k < 64; k++) a3 += sh2[k] * w3[k * NT + t];
        out[(size_t)gph * NT + t] = a3;
    }
}

extern "C" void kernel_launch(void* const* d_in, const int* in_sizes, int n_in,
                              void* d_out, int out_size, void* d_ws, size_t ws_size,
                              hipStream_t stream)
{
    const float* atom_fea = (const float*)d_in[0];
    const float* nbr_fea  = (const float*)d_in[1];
    const int*   nbr_idx  = (const int*)d_in[2];
    const int*   bm       = (const int*)d_in[3];
    const float* emb_w    = (const float*)d_in[4];
    const float* emb_b    = (const float*)d_in[5];
    const float* emb_ln_g = (const float*)d_in[6];
    const float* emb_ln_b = (const float*)d_in[7];
    const float* edge_w   = (const float*)d_in[8];
    const float* edge_b   = (const float*)d_in[9];
    const float* conv_w1  = (const float*)d_in[10];
    const float* conv_b1  = (const float*)d_in[11];
    const float* conv_w2  = (const float*)d_in[12];
    const float* conv_b2  = (const float*)d_in[13];
    const float* ln_g     = (const float*)d_in[14];
    const float* ln_b     = (const float*)d_in[15];
    const float* out_w1   = (const float*)d_in[16];
    const float* out_b1   = (const float*)d_in[17];
    const float* out_w2   = (const float*)d_in[18];
    const float* out_b2   = (const float*)d_in[19];
    const float* out_w3   = (const float*)d_in[20];
    const float* out_b3   = (const float*)d_in[21];
    float* out = (float*)d_out;

    // ---- workspace layout (256B-aligned regions) ----
    char* base = (char*)d_ws;
    size_t off = 0;
    auto alloc = [&](size_t bytes) -> char* {
        char* p = base + off;
        off = (off + bytes + 255) & ~(size_t)255;
        return p;
    };
    float*  xbuf    = (float*) alloc((size_t)N_NODES * HD * 4);
    float*  aggr    = (float*) alloc((size_t)N_NODES * HD * 4);
    float*  cnt     = (float*) alloc((size_t)N_NODES * 4);
    float*  crystal = (float*) alloc((size_t)N_GRAPHS * HD * 4);
    float*  gcnt    = (float*) alloc((size_t)N_GRAPHS * 4);
    ushort* x_bf    = (ushort*)alloc((size_t)N_NODES * HD * 2);
    ushort* e_bf    = (ushort*)alloc((size_t)N_EDGES * HD * 2);
    ushort* w1s     = (ushort*)alloc((size_t)NLAYERS * 65536 * 2);
    ushort* w2s     = (ushort*)alloc((size_t)NLAYERS * 32768 * 2);
    int*    cnt_i   = (int*)   alloc((size_t)N_NODES * 4);
    int*    cur     = (int*)   alloc((size_t)N_NODES * 4);
    int*    ssrc    = (int*)   alloc((size_t)N_EDGES * 4);
    int*    sdst    = (int*)   alloc((size_t)N_EDGES * 4);
    int*    posof   = (int*)   alloc((size_t)N_EDGES * 4);

    // weights -> swizzled bf16
    k_swz_w1<<<(NLAYERS * 65536) / 256, 256, 0, stream>>>(conv_w1, w1s);
    k_swz_w2<<<(NLAYERS * 32768) / 256, 256, 0, stream>>>(conv_w2, w2s);

    // zero aggr (layer 0 only; k_post re-zeroes for later layers)
    k_zero<<<(N_NODES * HD) / 256, 256, 0, stream>>>(aggr, N_NODES * HD);
    // zero cnt + crystal + gcnt (contiguous region) and cnt_i
    int zn = N_NODES + N_GRAPHS * HD + N_GRAPHS + 128;
    k_zero<<<(zn + 255) / 256, 256, 0, stream>>>(cnt, zn);
    k_zero<<<(N_NODES + 255) / 256, 256, 0, stream>>>((float*)cnt_i, N_NODES);

    // counting sort of edges by dst
    k_hist<<<N_EDGES / 256, 256, 0, stream>>>(nbr_idx, cnt_i);
    k_scan<<<1, 1024, 0, stream>>>(cnt_i, cur, cnt);
    k_scatter<<<N_EDGES / 256, 256, 0, stream>>>(nbr_idx, cur, ssrc, sdst, posof);

    k_node_embed<<<N_NODES, 128, 0, stream>>>(atom_fea, emb_w, emb_b, emb_ln_g, emb_ln_b, xbuf, x_bf);
    k_edge_embed<<<N_EDGES / ETILE, 128, 0, stream>>>(nbr_fea, edge_w, edge_b, posof, e_bf);
    k_gcount<<<(N_NODES + 255) / 256, 256, 0, stream>>>(bm, gcnt);

    for (int l = 0; l < NLAYERS; ++l) {
        k_conv_mfma<<<N_EDGES / 128, 256, 0, stream>>>(
            x_bf, e_bf, ssrc, sdst,
            w1s + (size_t)l * 65536, conv_b1 + (size_t)l * 256,
            w2s + (size_t)l * 32768, conv_b2 + (size_t)l * 128,
            aggr);
        k_post<<<N_NODES / 8, 256, 0, stream>>>(aggr, cnt, ln_g + (size_t)l * HD, ln_b + (size_t)l * HD, xbuf, x_bf);
    }

    k_gaggr<<<N_NODES, 128, 0, stream>>>(xbuf, bm, crystal);
    k_readout<<<N_GRAPHS, 128, 0, stream>>>(crystal, gcnt, out_w1, out_b1, out_w2, out_b2, out_w3, out_b3, out);
}